// Round 6
// baseline (261.334 us; speedup 1.0000x reference)
//
#include <hip/hip_runtime.h>
#include <hip/hip_bf16.h>

// ---------------------------------------------------------------------------
// GAT 2-layer forward on MI355X.
//   CSR build via two-level bucket sort (bucket hist -> scan -> coarse scatter
//   of packed records -> per-bucket fine pass writing rowptr + esrc, self-loop
//   appended as last slot per node).
//   layer: gemm fp32 (N x 128 @ 128 x 128, fused att dots) -> bf16 h
//          per-dst single-pass softmax agg, shuffle-staged edges -> fp32 o
//   pool: 2-phase (G x 16 partials, then reduce + logits)
// ---------------------------------------------------------------------------

#define THREADS 256
#define PSLICE 16
#define BUK_S 196        // nodes per bucket (NBUK = ceil(N/196) = 256 for N=50000)
#define SORT_BLOCKS 128

static __device__ __forceinline__ unsigned short f2bf(float f) {
    unsigned int u = __float_as_uint(f);
    return (unsigned short)((u + 0x7fffu + ((u >> 16) & 1u)) >> 16);  // RNE
}
static __device__ __forceinline__ float bf2f(unsigned short b) {
    return __uint_as_float(((unsigned int)b) << 16);
}

// ---- bucket sort pass A: per-bucket edge counts (LDS-staged) ----
__global__ __launch_bounds__(THREADS) void k_bukhist(const int* __restrict__ dst,
                                                     int* __restrict__ bcount, int E_, int chunk) {
    __shared__ int hist[THREADS];
    hist[threadIdx.x] = 0;
    __syncthreads();
    int e0 = blockIdx.x * chunk;
    int e1 = min(e0 + chunk, E_);
    for (int e = e0 + threadIdx.x; e < e1; e += THREADS)
        atomicAdd(&hist[dst[e] / BUK_S], 1);
    __syncthreads();
    int c = hist[threadIdx.x];
    if (c) atomicAdd(&bcount[threadIdx.x], c);
}

// ---- pass B: scan bucket counts -> staging bases + CSR bases (+self-loops) ----
__global__ __launch_bounds__(THREADS) void k_bukscan(const int* __restrict__ bcount,
                                                     int* __restrict__ sbase,
                                                     int* __restrict__ gcur,
                                                     int* __restrict__ cbase,
                                                     int nbuk, int Nn) {
    __shared__ int s[THREADS];
    int tid = threadIdx.x;
    int v = (tid < nbuk) ? bcount[tid] : 0;
    s[tid] = v;
    __syncthreads();
    for (int off = 1; off < THREADS; off <<= 1) {
        int t = (tid >= off) ? s[tid - off] : 0;
        __syncthreads();
        s[tid] += t;
        __syncthreads();
    }
    int excl1 = s[tid] - v;
    if (tid < nbuk) { sbase[tid] = excl1; gcur[tid] = excl1; }
    int n0 = tid * BUK_S;
    int ns = (tid < nbuk) ? min(BUK_S, Nn - n0) : 0;
    int v2 = v + ns;
    __syncthreads();
    s[tid] = v2;
    __syncthreads();
    for (int off = 1; off < THREADS; off <<= 1) {
        int t = (tid >= off) ? s[tid - off] : 0;
        __syncthreads();
        s[tid] += t;
        __syncthreads();
    }
    if (tid < nbuk) cbase[tid] = s[tid] - v2;
}

// ---- pass C: coarse scatter of packed records into bucket staging ----
__global__ __launch_bounds__(THREADS) void k_bukscatter(const int* __restrict__ src,
                                                        const int* __restrict__ dst,
                                                        int* __restrict__ gcur,
                                                        unsigned int* __restrict__ rec,
                                                        int E_, int chunk) {
    __shared__ int hist[THREADS];
    __shared__ int base[THREADS];
    hist[threadIdx.x] = 0;
    __syncthreads();
    int e0 = blockIdx.x * chunk;
    int e1 = min(e0 + chunk, E_);
    for (int e = e0 + threadIdx.x; e < e1; e += THREADS)
        atomicAdd(&hist[dst[e] / BUK_S], 1);
    __syncthreads();
    int c = hist[threadIdx.x];
    if (c) base[threadIdx.x] = atomicAdd(&gcur[threadIdx.x], c);
    hist[threadIdx.x] = 0;
    __syncthreads();
    for (int e = e0 + threadIdx.x; e < e1; e += THREADS) {
        int d = dst[e];
        int b = d / BUK_S;
        int r = atomicAdd(&hist[b], 1);
        rec[base[b] + r] = (unsigned int)src[e] | ((unsigned int)(d - b * BUK_S) << 17);
    }
}

// ---- pass D: per-bucket fine pass -> rowptr + esrc (self-loop last slot) ----
__global__ __launch_bounds__(THREADS) void k_csr(const unsigned int* __restrict__ rec,
                                                 const int* __restrict__ sbase,
                                                 const int* __restrict__ bcount,
                                                 const int* __restrict__ cbase,
                                                 int* __restrict__ rowptr,
                                                 int* __restrict__ esrc,
                                                 int Nn, int nbuk, int Etot) {
    __shared__ int cnt[THREADS];
    __shared__ int s[THREADS];
    __shared__ int cur[THREADS];
    int b = blockIdx.x;
    int tid = threadIdx.x;
    int n0 = b * BUK_S;
    int ns = min(BUK_S, Nn - n0);
    int cnt_e = bcount[b];
    int rbase = sbase[b];
    int cb = cbase[b];

    cnt[tid] = 0;
    __syncthreads();
    for (int i = tid; i < cnt_e; i += THREADS)
        atomicAdd(&cnt[rec[rbase + i] >> 17], 1);
    __syncthreads();
    int v = (tid < ns) ? cnt[tid] + 1 : 0;   // +1 self-loop
    s[tid] = v;
    __syncthreads();
    for (int off = 1; off < THREADS; off <<= 1) {
        int t = (tid >= off) ? s[tid - off] : 0;
        __syncthreads();
        s[tid] += t;
        __syncthreads();
    }
    int excl = s[tid] - v;
    __syncthreads();
    s[tid] = excl;          // keep exclusive offsets for self-loop placement
    cur[tid] = excl;
    if (tid < ns) rowptr[n0 + tid] = cb + excl;
    if (b == nbuk - 1 && tid == 0) rowptr[Nn] = Etot;
    __syncthreads();
    for (int i = tid; i < cnt_e; i += THREADS) {
        unsigned int r = rec[rbase + i];
        int l = r >> 17;
        int slot = atomicAdd(&cur[l], 1);
        esrc[cb + slot] = (int)(r & 0x1FFFFu);
    }
    __syncthreads();
    if (tid < ns) esrc[cb + s[tid] + cnt[tid]] = n0 + tid;   // self-loop last
}

// H = X(gathered) @ W ; 32 rows x 128 cols per block; fp32 compute.
// Writes H as bf16 (only the agg gather consumes it) + fused attention dots.
__global__ __launch_bounds__(THREADS) void k_gemm128(const float* __restrict__ X,
                                                     const int* __restrict__ idx,
                                                     const float* __restrict__ W,
                                                     const float* __restrict__ a_s,
                                                     const float* __restrict__ a_d,
                                                     unsigned short* __restrict__ outb,
                                                     float* __restrict__ as_,
                                                     float* __restrict__ ad_, int Nrows) {
    __shared__ float Wl[128 * 128];   // 64 KB
    __shared__ float xT[128 * 32];    // 16 KB, transposed x tile
    {
        const float4* W4 = (const float4*)W;
        float4* Wl4 = (float4*)Wl;
        #pragma unroll
        for (int i = 0; i < 16; ++i) Wl4[threadIdx.x + i * THREADS] = W4[threadIdx.x + i * THREADS];
    }
    {
        int r = threadIdx.x >> 3;            // 0..31
        int c0 = (threadIdx.x & 7) * 16;     // 0..112
        int R = blockIdx.x * 32 + r;
        if (R < Nrows) {
            int g = idx ? idx[R] : R;
            const float* xrow = X + (size_t)g * 128;
            #pragma unroll
            for (int i = 0; i < 4; ++i) {
                float4 v = *(const float4*)&xrow[c0 + i * 4];
                xT[(c0 + i * 4 + 0) * 32 + r] = v.x;
                xT[(c0 + i * 4 + 1) * 32 + r] = v.y;
                xT[(c0 + i * 4 + 2) * 32 + r] = v.z;
                xT[(c0 + i * 4 + 3) * 32 + r] = v.w;
            }
        } else {
            #pragma unroll
            for (int i = 0; i < 16; ++i) xT[(c0 + i) * 32 + r] = 0.f;
        }
    }
    __syncthreads();

    int j0 = (threadIdx.x & 31) * 4;   // col group
    int r0 = (threadIdx.x >> 5) * 4;   // row group
    float acc[4][4] = {};
    #pragma unroll 8
    for (int k = 0; k < 128; ++k) {
        float4 wv = *(const float4*)&Wl[k * 128 + j0];
        float4 xv = *(const float4*)&xT[k * 32 + r0];
        float xr[4] = {xv.x, xv.y, xv.z, xv.w};
        float wr[4] = {wv.x, wv.y, wv.z, wv.w};
        #pragma unroll
        for (int r = 0; r < 4; ++r)
            #pragma unroll
            for (int c = 0; c < 4; ++c) acc[r][c] = fmaf(xr[r], wr[c], acc[r][c]);
    }
    int Rb = blockIdx.x * 32 + r0;
    #pragma unroll
    for (int r = 0; r < 4; ++r) {
        int Rw = Rb + r;
        if (Rw < Nrows) {
            ushort4 o;
            o.x = f2bf(acc[r][0]);
            o.y = f2bf(acc[r][1]);
            o.z = f2bf(acc[r][2]);
            o.w = f2bf(acc[r][3]);
            *(ushort4*)&outb[(size_t)Rw * 128 + j0] = o;
        }
    }
    // fused attention dots
    float4 asv = *(const float4*)&a_s[j0];
    float4 adv = *(const float4*)&a_d[j0];
    #pragma unroll
    for (int r = 0; r < 4; ++r) {
        float ps = acc[r][0] * asv.x + acc[r][1] * asv.y + acc[r][2] * asv.z + acc[r][3] * asv.w;
        float pd = acc[r][0] * adv.x + acc[r][1] * adv.y + acc[r][2] * adv.z + acc[r][3] * adv.w;
        #pragma unroll
        for (int o = 16; o; o >>= 1) {
            ps += __shfl_xor(ps, o);
            pd += __shfl_xor(pd, o);
        }
        if ((threadIdx.x & 31) == 0) {
            int Rw = Rb + r;
            if (Rw < Nrows) {
                as_[Rw] = ps;
                ad_[Rw] = pd;
            }
        }
    }
}

// wave per dst node: single-pass softmax agg. Edges staged in chunks of 64:
// lane j computes (s_j, p_j) for edge c0+j once (coalesced esrc load, one exp
// per edge), z via shfl_xor reduce; inner loop broadcasts (s,p) with __shfl
// so the bf16 h-row gathers have no load-load dependence and pipeline deeply.
__global__ __launch_bounds__(THREADS) void k_agg(const unsigned short* __restrict__ hb,
                                                 const float* __restrict__ as_,
                                                 const float* __restrict__ ad_,
                                                 const int* __restrict__ rowptr,
                                                 const int* __restrict__ esrc,
                                                 const float* __restrict__ bias,
                                                 float* __restrict__ out, int Nn) {
    int d = blockIdx.x * 4 + (threadIdx.x >> 6);
    int lane = threadIdx.x & 63;
    if (d >= Nn) return;
    int beg = rowptr[d], end = rowptr[d + 1];
    float adv = ad_[d];
    float z = 0.f, accx = 0.f, accy = 0.f;
    for (int c0 = beg; c0 < end; c0 += 64) {
        int cn = end - c0;
        if (cn > 64) cn = 64;
        int sl = 0;
        float pl = 0.f;
        if (lane < cn) {
            sl = esrc[c0 + lane];
            float e = as_[sl] + adv;
            e = (e > 0.f) ? e : 0.2f * e;
            pl = __expf(e);
        }
        float pz = pl;
        #pragma unroll
        for (int o = 32; o; o >>= 1) pz += __shfl_xor(pz, o);
        z += pz;
        #pragma unroll 4
        for (int j = 0; j < cn; ++j) {
            int s = __shfl(sl, j);
            float p = __shfl(pl, j);
            unsigned int hv = *(const unsigned int*)&hb[(size_t)s * 128 + lane * 2];
            accx += p * bf2f((unsigned short)(hv & 0xffffu));
            accy += p * bf2f((unsigned short)(hv >> 16));
        }
    }
    float inv = 1.f / z;
    float2 o;
    o.x = fmaxf(accx * inv + bias[lane * 2 + 0], 0.f);
    o.y = fmaxf(accy * inv + bias[lane * 2 + 1], 0.f);
    *(float2*)&out[(size_t)d * 128 + lane * 2] = o;
}

// phase 1: grid (G, PSLICE); each block sums a strided slice of graph g's rows
__global__ __launch_bounds__(THREADS) void k_pool_partial(const float* __restrict__ x,
                                                          const int* __restrict__ batch,
                                                          float* __restrict__ part, int Nn) {
    int g = blockIdx.x;
    int s = blockIdx.y;
    int a = 0, b = Nn;
    while (a < b) { int mid = (a + b) >> 1; if (batch[mid] < g) a = mid + 1; else b = mid; }
    int lo = a;
    b = Nn;
    while (a < b) { int mid = (a + b) >> 1; if (batch[mid] < g + 1) a = mid + 1; else b = mid; }
    int hi = a;

    int j = threadIdx.x & 127;
    int half = threadIdx.x >> 7;   // 2 rows per iteration
    float acc = 0.f;
    for (int n = lo + s * 2 + half; n < hi; n += 2 * PSLICE) acc += x[(size_t)n * 128 + j];
    __shared__ float sred[THREADS];
    sred[threadIdx.x] = acc;
    __syncthreads();
    if (half == 0) part[((size_t)g * PSLICE + s) * 128 + j] = sred[j] + sred[128 + j];
}

// phase 2: one block (128 threads) per graph: reduce partials, mean, logits
__global__ __launch_bounds__(128) void k_pool_final(const float* __restrict__ part,
                                                    const int* __restrict__ batch,
                                                    const float* __restrict__ Wc,
                                                    const float* __restrict__ bc,
                                                    float* __restrict__ out, int Nn, int Gn) {
    int g = blockIdx.x;
    int j = threadIdx.x;
    int a = 0, b = Nn;
    while (a < b) { int mid = (a + b) >> 1; if (batch[mid] < g) a = mid + 1; else b = mid; }
    int lo = a;
    b = Nn;
    while (a < b) { int mid = (a + b) >> 1; if (batch[mid] < g + 1) a = mid + 1; else b = mid; }
    int cnt = a - lo;

    float s = 0.f;
    #pragma unroll
    for (int t = 0; t < PSLICE; ++t) s += part[((size_t)g * PSLICE + t) * 128 + j];
    float mean = s / fmaxf((float)cnt, 1.f);
    out[Gn + (size_t)g * 128 + j] = mean;

    __shared__ float sred[128];
    sred[j] = mean * Wc[j];
    __syncthreads();
    for (int off = 64; off >= 1; off >>= 1) {
        if (j < off) sred[j] += sred[j + off];
        __syncthreads();
    }
    if (j == 0) out[g] = sred[0] + bc[0];
}

static inline size_t align256(size_t x) { return (x + 255) & ~(size_t)255; }

extern "C" void kernel_launch(void* const* d_in, const int* in_sizes, int n_in,
                              void* d_out, int out_size, void* d_ws, size_t ws_size,
                              hipStream_t stream) {
    const int* x_lex = (const int*)d_in[0];
    const int* eidx  = (const int*)d_in[1];
    const int* batch = (const int*)d_in[2];
    const float* emb = (const float*)d_in[3];
    const float* W1  = (const float*)d_in[4];
    const float* a_s1 = (const float*)d_in[5];
    const float* a_d1 = (const float*)d_in[6];
    const float* b1  = (const float*)d_in[7];
    const float* W2  = (const float*)d_in[8];
    const float* a_s2 = (const float*)d_in[9];
    const float* a_d2 = (const float*)d_in[10];
    const float* b2  = (const float*)d_in[11];
    const float* Wc  = (const float*)d_in[12];
    const float* bc  = (const float*)d_in[13];

    const int N = in_sizes[0];
    const int E = in_sizes[1] / 2;
    const int G = out_size / 129;      // out = [G logits] + [G x 128 pool]
    const int Etot = E + N;
    const int* esrc_in = eidx;
    const int* edst_in = eidx + E;
    const int NBUK = (N + BUK_S - 1) / BUK_S;   // 256 for N=50000

    // workspace carve
    char* p = (char*)d_ws;
    unsigned short* hb = (unsigned short*)p;  p += align256((size_t)N * 128 * 2);
    float* obuf = (float*)p;            p += align256((size_t)N * 128 * 4);
    float* as_  = (float*)p;            p += align256((size_t)N * 4);
    float* ad_  = (float*)p;            p += align256((size_t)N * 4);
    int* bcount = (int*)p;              p += align256((size_t)NBUK * 4);
    int* sbase  = (int*)p;              p += align256((size_t)NBUK * 4);
    int* gcur   = (int*)p;              p += align256((size_t)NBUK * 4);
    int* cbase  = (int*)p;              p += align256((size_t)NBUK * 4);
    int* rowptr = (int*)p;              p += align256((size_t)(N + 1) * 4);
    unsigned int* rec = (unsigned int*)p; p += align256((size_t)E * 4);
    int* esrc   = (int*)p;              p += align256((size_t)Etot * 4);
    float* part = (float*)p;            p += align256((size_t)G * PSLICE * 128 * 4);

    const int chunk = (E + SORT_BLOCKS - 1) / SORT_BLOCKS;

    // ---- CSR build via bucket sort ----
    hipMemsetAsync(bcount, 0, (size_t)NBUK * 4, stream);
    k_bukhist<<<SORT_BLOCKS, THREADS, 0, stream>>>(edst_in, bcount, E, chunk);
    k_bukscan<<<1, THREADS, 0, stream>>>(bcount, sbase, gcur, cbase, NBUK, N);
    k_bukscatter<<<SORT_BLOCKS, THREADS, 0, stream>>>(esrc_in, edst_in, gcur, rec, E, chunk);
    k_csr<<<NBUK, THREADS, 0, stream>>>(rec, sbase, bcount, cbase, rowptr, esrc, N, NBUK, Etot);

    const int gemm_grid = (N + 31) / 32;
    const int node_grid = (N + 3) / 4;

    // ---- layer 1 ----
    k_gemm128<<<gemm_grid, THREADS, 0, stream>>>(emb, x_lex, W1, a_s1, a_d1, hb, as_, ad_, N);
    k_agg<<<node_grid, THREADS, 0, stream>>>(hb, as_, ad_, rowptr, esrc, b1, obuf, N);

    // ---- layer 2 ----
    k_gemm128<<<gemm_grid, THREADS, 0, stream>>>(obuf, nullptr, W2, a_s2, a_d2, hb, as_, ad_, N);
    k_agg<<<node_grid, THREADS, 0, stream>>>(hb, as_, ad_, rowptr, esrc, b2, obuf, N);

    // ---- pool + logits ----
    k_pool_partial<<<dim3(G, PSLICE), THREADS, 0, stream>>>(obuf, batch, part, N);
    k_pool_final<<<G, 128, 0, stream>>>(part, batch, Wc, bc, (float*)d_out, N, G);
}

// Round 7
// 228.206 us; speedup vs baseline: 1.1452x; 1.1452x over previous
//
#include <hip/hip_runtime.h>
#include <hip/hip_bf16.h>

// ---------------------------------------------------------------------------
// GAT 2-layer forward on MI355X.
//   CSR build via two-level bucket sort.
//   layer: MFMA split-bf16 gemm (3-term: xh*Wh + xh*Wl + xl*Wh, fp32 acc,
//          fused att dots) -> bf16 h ; per-dst single-pass softmax agg -> fp32
//   pool: 2-phase (G x 16 partials, then reduce + logits)
// ---------------------------------------------------------------------------

#define THREADS 256
#define PSLICE 16
#define BUK_S 196        // nodes per bucket (NBUK = 256 for N=50000)
#define SORT_BLOCKS 128

typedef __attribute__((ext_vector_type(8))) short short8v;   // 8 bf16
typedef __attribute__((ext_vector_type(4))) float f32x4;

static __device__ __forceinline__ unsigned short f2bf(float f) {
    unsigned int u = __float_as_uint(f);
    return (unsigned short)((u + 0x7fffu + ((u >> 16) & 1u)) >> 16);  // RNE
}
static __device__ __forceinline__ float bf2f(unsigned short b) {
    return __uint_as_float(((unsigned int)b) << 16);
}

// ---- W split + fragment-major reorder: WB[((c*4+t)*64 + lane)*8 + j] ----
// value = W[k][n], k = t*32 + (lane>>4)*8 + j, n = c*16 + (lane&15)
__global__ __launch_bounds__(THREADS) void k_wsplit(const float* __restrict__ W,
                                                    unsigned short* __restrict__ Wh,
                                                    unsigned short* __restrict__ Wl) {
    int t = blockIdx.x * THREADS + threadIdx.x;
    if (t >= 128 * 128) return;
    int k = t >> 7, n = t & 127;
    float w = W[t];
    unsigned short h = f2bf(w);
    unsigned short lo = f2bf(w - bf2f(h));
    int c = n >> 4, nl = n & 15, tt = k >> 5, kk = k & 31, g = kk >> 3, j = kk & 7;
    int o = (((c * 4 + tt) * 64) + g * 16 + nl) * 8 + j;
    Wh[o] = h;
    Wl[o] = lo;
}

// ---- bucket sort pass A: per-bucket edge counts (LDS-staged) ----
__global__ __launch_bounds__(THREADS) void k_bukhist(const int* __restrict__ dst,
                                                     int* __restrict__ bcount, int E_, int chunk) {
    __shared__ int hist[THREADS];
    hist[threadIdx.x] = 0;
    __syncthreads();
    int e0 = blockIdx.x * chunk;
    int e1 = min(e0 + chunk, E_);
    for (int e = e0 + threadIdx.x; e < e1; e += THREADS)
        atomicAdd(&hist[dst[e] / BUK_S], 1);
    __syncthreads();
    int c = hist[threadIdx.x];
    if (c) atomicAdd(&bcount[threadIdx.x], c);
}

// ---- pass B: scan bucket counts -> staging bases + CSR bases (+self-loops) ----
__global__ __launch_bounds__(THREADS) void k_bukscan(const int* __restrict__ bcount,
                                                     int* __restrict__ sbase,
                                                     int* __restrict__ gcur,
                                                     int* __restrict__ cbase,
                                                     int nbuk, int Nn) {
    __shared__ int s[THREADS];
    int tid = threadIdx.x;
    int v = (tid < nbuk) ? bcount[tid] : 0;
    s[tid] = v;
    __syncthreads();
    for (int off = 1; off < THREADS; off <<= 1) {
        int t = (tid >= off) ? s[tid - off] : 0;
        __syncthreads();
        s[tid] += t;
        __syncthreads();
    }
    int excl1 = s[tid] - v;
    if (tid < nbuk) { sbase[tid] = excl1; gcur[tid] = excl1; }
    int n0 = tid * BUK_S;
    int ns = (tid < nbuk) ? min(BUK_S, Nn - n0) : 0;
    int v2 = v + ns;
    __syncthreads();
    s[tid] = v2;
    __syncthreads();
    for (int off = 1; off < THREADS; off <<= 1) {
        int t = (tid >= off) ? s[tid - off] : 0;
        __syncthreads();
        s[tid] += t;
        __syncthreads();
    }
    if (tid < nbuk) cbase[tid] = s[tid] - v2;
}

// ---- pass C: coarse scatter of packed records into bucket staging ----
__global__ __launch_bounds__(THREADS) void k_bukscatter(const int* __restrict__ src,
                                                        const int* __restrict__ dst,
                                                        int* __restrict__ gcur,
                                                        unsigned int* __restrict__ rec,
                                                        int E_, int chunk) {
    __shared__ int hist[THREADS];
    __shared__ int base[THREADS];
    hist[threadIdx.x] = 0;
    __syncthreads();
    int e0 = blockIdx.x * chunk;
    int e1 = min(e0 + chunk, E_);
    for (int e = e0 + threadIdx.x; e < e1; e += THREADS)
        atomicAdd(&hist[dst[e] / BUK_S], 1);
    __syncthreads();
    int c = hist[threadIdx.x];
    if (c) base[threadIdx.x] = atomicAdd(&gcur[threadIdx.x], c);
    hist[threadIdx.x] = 0;
    __syncthreads();
    for (int e = e0 + threadIdx.x; e < e1; e += THREADS) {
        int d = dst[e];
        int b = d / BUK_S;
        int r = atomicAdd(&hist[b], 1);
        rec[base[b] + r] = (unsigned int)src[e] | ((unsigned int)(d - b * BUK_S) << 17);
    }
}

// ---- pass D: per-bucket fine pass -> rowptr + esrc (self-loop last slot) ----
__global__ __launch_bounds__(THREADS) void k_csr(const unsigned int* __restrict__ rec,
                                                 const int* __restrict__ sbase,
                                                 const int* __restrict__ bcount,
                                                 const int* __restrict__ cbase,
                                                 int* __restrict__ rowptr,
                                                 int* __restrict__ esrc,
                                                 int Nn, int nbuk, int Etot) {
    __shared__ int cnt[THREADS];
    __shared__ int s[THREADS];
    __shared__ int cur[THREADS];
    int b = blockIdx.x;
    int tid = threadIdx.x;
    int n0 = b * BUK_S;
    int ns = min(BUK_S, Nn - n0);
    int cnt_e = bcount[b];
    int rbase = sbase[b];
    int cb = cbase[b];

    cnt[tid] = 0;
    __syncthreads();
    for (int i = tid; i < cnt_e; i += THREADS)
        atomicAdd(&cnt[rec[rbase + i] >> 17], 1);
    __syncthreads();
    int v = (tid < ns) ? cnt[tid] + 1 : 0;   // +1 self-loop
    s[tid] = v;
    __syncthreads();
    for (int off = 1; off < THREADS; off <<= 1) {
        int t = (tid >= off) ? s[tid - off] : 0;
        __syncthreads();
        s[tid] += t;
        __syncthreads();
    }
    int excl = s[tid] - v;
    __syncthreads();
    s[tid] = excl;
    cur[tid] = excl;
    if (tid < ns) rowptr[n0 + tid] = cb + excl;
    if (b == nbuk - 1 && tid == 0) rowptr[Nn] = Etot;
    __syncthreads();
    for (int i = tid; i < cnt_e; i += THREADS) {
        unsigned int r = rec[rbase + i];
        int l = r >> 17;
        int slot = atomicAdd(&cur[l], 1);
        esrc[cb + slot] = (int)(r & 0x1FFFFu);
    }
    __syncthreads();
    if (tid < ns) esrc[cb + s[tid] + cnt[tid]] = n0 + tid;   // self-loop last
}

// swizzled LDS index (ushort units) for x tiles: row-major [64][128] bf16,
// 16B-block XOR with (row&7) to kill ds_read_b128 bank conflicts.
static __device__ __forceinline__ int xsw(int r, int c) {
    return (((r * 16 + (c >> 3)) ^ (r & 7)) << 3) | (c & 7);
}

// H = X(gathered) @ W via MFMA split-bf16 (3 terms). Block: 64 rows x 128 cols,
// 4 waves, each wave 16 rows x 8 col-tiles of 16x16x32 MFMA.
// Writes H as bf16 + fused attention dots.
__global__ __launch_bounds__(THREADS) void k_gemm_mfma(const float* __restrict__ X,
                                                       const int* __restrict__ idx,
                                                       const unsigned short* __restrict__ WBh,
                                                       const unsigned short* __restrict__ WBl,
                                                       const float* __restrict__ a_s,
                                                       const float* __restrict__ a_d,
                                                       unsigned short* __restrict__ outb,
                                                       float* __restrict__ as_,
                                                       float* __restrict__ ad_, int Nrows) {
    __shared__ unsigned short xh[64 * 128];
    __shared__ unsigned short xl[64 * 128];

    // stage + split: 4 threads per row, 32 cols each (8 float4)
    {
        int r = threadIdx.x >> 2;            // 0..63
        int c0 = (threadIdx.x & 3) * 32;
        int R = blockIdx.x * 64 + r;
        if (R < Nrows) {
            int g = idx ? idx[R] : R;
            const float4* xrow = (const float4*)(X + (size_t)g * 128);
            #pragma unroll
            for (int i = 0; i < 8; ++i) {
                float4 v = xrow[(c0 >> 2) + i];
                int c = c0 + i * 4;
                ushort4 hh, ll;
                hh.x = f2bf(v.x); ll.x = f2bf(v.x - bf2f(hh.x));
                hh.y = f2bf(v.y); ll.y = f2bf(v.y - bf2f(hh.y));
                hh.z = f2bf(v.z); ll.z = f2bf(v.z - bf2f(hh.z));
                hh.w = f2bf(v.w); ll.w = f2bf(v.w - bf2f(hh.w));
                int o = xsw(r, c);
                *(ushort4*)&xh[o] = hh;
                *(ushort4*)&xl[o] = ll;
            }
        } else {
            #pragma unroll
            for (int i = 0; i < 8; ++i) {
                int o = xsw(r, c0 + i * 4);
                *(ushort4*)&xh[o] = make_ushort4(0, 0, 0, 0);
                *(ushort4*)&xl[o] = make_ushort4(0, 0, 0, 0);
            }
        }
    }
    __syncthreads();

    int wid = threadIdx.x >> 6;
    int lane = threadIdx.x & 63;
    int nl = lane & 15;
    int g = lane >> 4;
    int arow = wid * 16 + nl;     // A-frag row for this lane

    f32x4 acc[8];
    #pragma unroll
    for (int c = 0; c < 8; ++c) acc[c] = (f32x4){0.f, 0.f, 0.f, 0.f};

    #pragma unroll
    for (int t = 0; t < 4; ++t) {
        int ao = xsw(arow, t * 32 + g * 8);
        short8v ah = *(const short8v*)&xh[ao];
        short8v al = *(const short8v*)&xl[ao];
        #pragma unroll
        for (int c = 0; c < 8; ++c) {
            int bo = (((c * 4 + t) * 64) + lane) * 8;
            short8v bh = *(const short8v*)&WBh[bo];
            short8v bl = *(const short8v*)&WBl[bo];
            acc[c] = __builtin_amdgcn_mfma_f32_16x16x32_bf16(ah, bh, acc[c], 0, 0, 0);
            acc[c] = __builtin_amdgcn_mfma_f32_16x16x32_bf16(ah, bl, acc[c], 0, 0, 0);
            acc[c] = __builtin_amdgcn_mfma_f32_16x16x32_bf16(al, bh, acc[c], 0, 0, 0);
        }
    }

    // epilogue: C row = wid*16 + g*4 + r, col = c*16 + nl
    float asv[8], adv[8];
    #pragma unroll
    for (int c = 0; c < 8; ++c) {
        asv[c] = a_s[c * 16 + nl];
        adv[c] = a_d[c * 16 + nl];
    }
    int Rb = blockIdx.x * 64 + wid * 16 + g * 4;
    #pragma unroll
    for (int r = 0; r < 4; ++r) {
        int R = Rb + r;
        bool ok = (R < Nrows);
        float ps = 0.f, pd = 0.f;
        #pragma unroll
        for (int c = 0; c < 8; ++c) {
            float v = acc[c][r];
            if (ok) outb[(size_t)R * 128 + c * 16 + nl] = f2bf(v);
            ps = fmaf(v, asv[c], ps);
            pd = fmaf(v, adv[c], pd);
        }
        #pragma unroll
        for (int o = 8; o; o >>= 1) {
            ps += __shfl_xor(ps, o);
            pd += __shfl_xor(pd, o);
        }
        if (ok && nl == 0) {
            as_[R] = ps;
            ad_[R] = pd;
        }
    }
}

// wave per dst node: single-pass softmax agg (no max shift; |e| small by
// construction), bf16 h gather, fp32 accumulate, + bias, relu.
__global__ __launch_bounds__(THREADS) void k_agg(const unsigned short* __restrict__ hb,
                                                 const float* __restrict__ as_,
                                                 const float* __restrict__ ad_,
                                                 const int* __restrict__ rowptr,
                                                 const int* __restrict__ esrc,
                                                 const float* __restrict__ bias,
                                                 float* __restrict__ out, int Nn) {
    int d = blockIdx.x * 4 + (threadIdx.x >> 6);
    int lane = threadIdx.x & 63;
    if (d >= Nn) return;
    int beg = rowptr[d], end = rowptr[d + 1];
    float adv = ad_[d];
    float z = 0.f, accx = 0.f, accy = 0.f;
    #pragma unroll 2
    for (int k = beg; k < end; ++k) {
        int s = esrc[k];
        float e = as_[s] + adv;
        e = (e > 0.f) ? e : 0.2f * e;
        float p = __expf(e);
        unsigned int hv = *(const unsigned int*)&hb[(size_t)s * 128 + lane * 2];
        z += p;
        accx += p * bf2f((unsigned short)(hv & 0xffffu));
        accy += p * bf2f((unsigned short)(hv >> 16));
    }
    float inv = 1.f / z;
    float2 o;
    o.x = fmaxf(accx * inv + bias[lane * 2 + 0], 0.f);
    o.y = fmaxf(accy * inv + bias[lane * 2 + 1], 0.f);
    *(float2*)&out[(size_t)d * 128 + lane * 2] = o;
}

// phase 1: grid (G, PSLICE); each block sums a strided slice of graph g's rows
__global__ __launch_bounds__(THREADS) void k_pool_partial(const float* __restrict__ x,
                                                          const int* __restrict__ batch,
                                                          float* __restrict__ part, int Nn) {
    int g = blockIdx.x;
    int s = blockIdx.y;
    int a = 0, b = Nn;
    while (a < b) { int mid = (a + b) >> 1; if (batch[mid] < g) a = mid + 1; else b = mid; }
    int lo = a;
    b = Nn;
    while (a < b) { int mid = (a + b) >> 1; if (batch[mid] < g + 1) a = mid + 1; else b = mid; }
    int hi = a;

    int j = threadIdx.x & 127;
    int half = threadIdx.x >> 7;
    float acc = 0.f;
    for (int n = lo + s * 2 + half; n < hi; n += 2 * PSLICE) acc += x[(size_t)n * 128 + j];
    __shared__ float sred[THREADS];
    sred[threadIdx.x] = acc;
    __syncthreads();
    if (half == 0) part[((size_t)g * PSLICE + s) * 128 + j] = sred[j] + sred[128 + j];
}

// phase 2: one block (128 threads) per graph: reduce partials, mean, logits
__global__ __launch_bounds__(128) void k_pool_final(const float* __restrict__ part,
                                                    const int* __restrict__ batch,
                                                    const float* __restrict__ Wc,
                                                    const float* __restrict__ bc,
                                                    float* __restrict__ out, int Nn, int Gn) {
    int g = blockIdx.x;
    int j = threadIdx.x;
    int a = 0, b = Nn;
    while (a < b) { int mid = (a + b) >> 1; if (batch[mid] < g) a = mid + 1; else b = mid; }
    int lo = a;
    b = Nn;
    while (a < b) { int mid = (a + b) >> 1; if (batch[mid] < g + 1) a = mid + 1; else b = mid; }
    int cnt = a - lo;

    float s = 0.f;
    #pragma unroll
    for (int t = 0; t < PSLICE; ++t) s += part[((size_t)g * PSLICE + t) * 128 + j];
    float mean = s / fmaxf((float)cnt, 1.f);
    out[Gn + (size_t)g * 128 + j] = mean;

    __shared__ float sred[128];
    sred[j] = mean * Wc[j];
    __syncthreads();
    for (int off = 64; off >= 1; off >>= 1) {
        if (j < off) sred[j] += sred[j + off];
        __syncthreads();
    }
    if (j == 0) out[g] = sred[0] + bc[0];
}

static inline size_t align256(size_t x) { return (x + 255) & ~(size_t)255; }

extern "C" void kernel_launch(void* const* d_in, const int* in_sizes, int n_in,
                              void* d_out, int out_size, void* d_ws, size_t ws_size,
                              hipStream_t stream) {
    const int* x_lex = (const int*)d_in[0];
    const int* eidx  = (const int*)d_in[1];
    const int* batch = (const int*)d_in[2];
    const float* emb = (const float*)d_in[3];
    const float* W1  = (const float*)d_in[4];
    const float* a_s1 = (const float*)d_in[5];
    const float* a_d1 = (const float*)d_in[6];
    const float* b1  = (const float*)d_in[7];
    const float* W2  = (const float*)d_in[8];
    const float* a_s2 = (const float*)d_in[9];
    const float* a_d2 = (const float*)d_in[10];
    const float* b2  = (const float*)d_in[11];
    const float* Wc  = (const float*)d_in[12];
    const float* bc  = (const float*)d_in[13];

    const int N = in_sizes[0];
    const int E = in_sizes[1] / 2;
    const int G = out_size / 129;      // out = [G logits] + [G x 128 pool]
    const int Etot = E + N;
    const int* esrc_in = eidx;
    const int* edst_in = eidx + E;
    const int NBUK = (N + BUK_S - 1) / BUK_S;   // 256 for N=50000

    // workspace carve
    char* p = (char*)d_ws;
    unsigned short* hb = (unsigned short*)p;  p += align256((size_t)N * 128 * 2);
    float* obuf = (float*)p;            p += align256((size_t)N * 128 * 4);
    float* as_  = (float*)p;            p += align256((size_t)N * 4);
    float* ad_  = (float*)p;            p += align256((size_t)N * 4);
    int* bcount = (int*)p;              p += align256((size_t)NBUK * 4);
    int* sbase  = (int*)p;              p += align256((size_t)NBUK * 4);
    int* gcur   = (int*)p;              p += align256((size_t)NBUK * 4);
    int* cbase  = (int*)p;              p += align256((size_t)NBUK * 4);
    int* rowptr = (int*)p;              p += align256((size_t)(N + 1) * 4);
    unsigned int* rec = (unsigned int*)p; p += align256((size_t)E * 4);
    int* esrc   = (int*)p;              p += align256((size_t)Etot * 4);
    float* part = (float*)p;            p += align256((size_t)G * PSLICE * 128 * 4);
    unsigned short* WBh1 = (unsigned short*)p; p += align256((size_t)128 * 128 * 2);
    unsigned short* WBl1 = (unsigned short*)p; p += align256((size_t)128 * 128 * 2);
    unsigned short* WBh2 = (unsigned short*)p; p += align256((size_t)128 * 128 * 2);
    unsigned short* WBl2 = (unsigned short*)p; p += align256((size_t)128 * 128 * 2);

    const int chunk = (E + SORT_BLOCKS - 1) / SORT_BLOCKS;

    // ---- W split (fragment-major) ----
    k_wsplit<<<64, THREADS, 0, stream>>>(W1, WBh1, WBl1);
    k_wsplit<<<64, THREADS, 0, stream>>>(W2, WBh2, WBl2);

    // ---- CSR build via bucket sort ----
    hipMemsetAsync(bcount, 0, (size_t)NBUK * 4, stream);
    k_bukhist<<<SORT_BLOCKS, THREADS, 0, stream>>>(edst_in, bcount, E, chunk);
    k_bukscan<<<1, THREADS, 0, stream>>>(bcount, sbase, gcur, cbase, NBUK, N);
    k_bukscatter<<<SORT_BLOCKS, THREADS, 0, stream>>>(esrc_in, edst_in, gcur, rec, E, chunk);
    k_csr<<<NBUK, THREADS, 0, stream>>>(rec, sbase, bcount, cbase, rowptr, esrc, N, NBUK, Etot);

    const int gemm_grid = (N + 63) / 64;
    const int node_grid = (N + 3) / 4;

    // ---- layer 1 ----
    k_gemm_mfma<<<gemm_grid, THREADS, 0, stream>>>(emb, x_lex, WBh1, WBl1, a_s1, a_d1, hb, as_, ad_, N);
    k_agg<<<node_grid, THREADS, 0, stream>>>(hb, as_, ad_, rowptr, esrc, b1, obuf, N);

    // ---- layer 2 ----
    k_gemm_mfma<<<gemm_grid, THREADS, 0, stream>>>(obuf, nullptr, WBh2, WBl2, a_s2, a_d2, hb, as_, ad_, N);
    k_agg<<<node_grid, THREADS, 0, stream>>>(hb, as_, ad_, rowptr, esrc, b2, obuf, N);

    // ---- pool + logits ----
    k_pool_partial<<<dim3(G, PSLICE), THREADS, 0, stream>>>(obuf, batch, part, N);
    k_pool_final<<<G, 128, 0, stream>>>(part, batch, Wc, bc, (float*)d_out, N, G);
}

// Round 8
// 213.841 us; speedup vs baseline: 1.2221x; 1.0672x over previous
//
#include <hip/hip_runtime.h>
#include <hip/hip_bf16.h>

// ---------------------------------------------------------------------------
// GAT 2-layer forward on MI355X.
//   CSR build via two-level bucket sort (also emits edst per slot).
//   layer: MFMA split-bf16 gemm (3-term, fused att dots) -> bf16 h
//          edge-parallel p = exp(lrelu(as+ad)) pre-pass
//          per-dst agg: 8-deep pipelined h gather, z = sum p -> fp32 o
//   pool: 2-phase (G x 16 partials, then reduce + logits)
// ---------------------------------------------------------------------------

#define THREADS 256
#define PSLICE 16
#define BUK_S 196        // nodes per bucket (NBUK = 256 for N=50000)
#define SORT_BLOCKS 128

typedef __attribute__((ext_vector_type(8))) short short8v;   // 8 bf16
typedef __attribute__((ext_vector_type(4))) float f32x4;

static __device__ __forceinline__ unsigned short f2bf(float f) {
    unsigned int u = __float_as_uint(f);
    return (unsigned short)((u + 0x7fffu + ((u >> 16) & 1u)) >> 16);  // RNE
}
static __device__ __forceinline__ float bf2f(unsigned short b) {
    return __uint_as_float(((unsigned int)b) << 16);
}

// ---- W split + fragment-major reorder: WB[((c*4+t)*64 + lane)*8 + j] ----
__global__ __launch_bounds__(THREADS) void k_wsplit(const float* __restrict__ W,
                                                    unsigned short* __restrict__ Wh,
                                                    unsigned short* __restrict__ Wl) {
    int t = blockIdx.x * THREADS + threadIdx.x;
    if (t >= 128 * 128) return;
    int k = t >> 7, n = t & 127;
    float w = W[t];
    unsigned short h = f2bf(w);
    unsigned short lo = f2bf(w - bf2f(h));
    int c = n >> 4, nl = n & 15, tt = k >> 5, kk = k & 31, g = kk >> 3, j = kk & 7;
    int o = (((c * 4 + tt) * 64) + g * 16 + nl) * 8 + j;
    Wh[o] = h;
    Wl[o] = lo;
}

// ---- bucket sort pass A: per-bucket edge counts (LDS-staged) ----
__global__ __launch_bounds__(THREADS) void k_bukhist(const int* __restrict__ dst,
                                                     int* __restrict__ bcount, int E_, int chunk) {
    __shared__ int hist[THREADS];
    hist[threadIdx.x] = 0;
    __syncthreads();
    int e0 = blockIdx.x * chunk;
    int e1 = min(e0 + chunk, E_);
    for (int e = e0 + threadIdx.x; e < e1; e += THREADS)
        atomicAdd(&hist[dst[e] / BUK_S], 1);
    __syncthreads();
    int c = hist[threadIdx.x];
    if (c) atomicAdd(&bcount[threadIdx.x], c);
}

// ---- pass B: scan bucket counts -> staging bases + CSR bases (+self-loops) ----
__global__ __launch_bounds__(THREADS) void k_bukscan(const int* __restrict__ bcount,
                                                     int* __restrict__ sbase,
                                                     int* __restrict__ gcur,
                                                     int* __restrict__ cbase,
                                                     int nbuk, int Nn) {
    __shared__ int s[THREADS];
    int tid = threadIdx.x;
    int v = (tid < nbuk) ? bcount[tid] : 0;
    s[tid] = v;
    __syncthreads();
    for (int off = 1; off < THREADS; off <<= 1) {
        int t = (tid >= off) ? s[tid - off] : 0;
        __syncthreads();
        s[tid] += t;
        __syncthreads();
    }
    int excl1 = s[tid] - v;
    if (tid < nbuk) { sbase[tid] = excl1; gcur[tid] = excl1; }
    int n0 = tid * BUK_S;
    int ns = (tid < nbuk) ? min(BUK_S, Nn - n0) : 0;
    int v2 = v + ns;
    __syncthreads();
    s[tid] = v2;
    __syncthreads();
    for (int off = 1; off < THREADS; off <<= 1) {
        int t = (tid >= off) ? s[tid - off] : 0;
        __syncthreads();
        s[tid] += t;
        __syncthreads();
    }
    if (tid < nbuk) cbase[tid] = s[tid] - v2;
}

// ---- pass C: coarse scatter of packed records into bucket staging ----
__global__ __launch_bounds__(THREADS) void k_bukscatter(const int* __restrict__ src,
                                                        const int* __restrict__ dst,
                                                        int* __restrict__ gcur,
                                                        unsigned int* __restrict__ rec,
                                                        int E_, int chunk) {
    __shared__ int hist[THREADS];
    __shared__ int base[THREADS];
    hist[threadIdx.x] = 0;
    __syncthreads();
    int e0 = blockIdx.x * chunk;
    int e1 = min(e0 + chunk, E_);
    for (int e = e0 + threadIdx.x; e < e1; e += THREADS)
        atomicAdd(&hist[dst[e] / BUK_S], 1);
    __syncthreads();
    int c = hist[threadIdx.x];
    if (c) base[threadIdx.x] = atomicAdd(&gcur[threadIdx.x], c);
    hist[threadIdx.x] = 0;
    __syncthreads();
    for (int e = e0 + threadIdx.x; e < e1; e += THREADS) {
        int d = dst[e];
        int b = d / BUK_S;
        int r = atomicAdd(&hist[b], 1);
        rec[base[b] + r] = (unsigned int)src[e] | ((unsigned int)(d - b * BUK_S) << 17);
    }
}

// ---- pass D: per-bucket fine pass -> rowptr + esrc + edst ----
__global__ __launch_bounds__(THREADS) void k_csr(const unsigned int* __restrict__ rec,
                                                 const int* __restrict__ sbase,
                                                 const int* __restrict__ bcount,
                                                 const int* __restrict__ cbase,
                                                 int* __restrict__ rowptr,
                                                 int* __restrict__ esrc,
                                                 int* __restrict__ edst,
                                                 int Nn, int nbuk, int Etot) {
    __shared__ int cnt[THREADS];
    __shared__ int s[THREADS];
    __shared__ int cur[THREADS];
    int b = blockIdx.x;
    int tid = threadIdx.x;
    int n0 = b * BUK_S;
    int ns = min(BUK_S, Nn - n0);
    int cnt_e = bcount[b];
    int rbase = sbase[b];
    int cb = cbase[b];

    cnt[tid] = 0;
    __syncthreads();
    for (int i = tid; i < cnt_e; i += THREADS)
        atomicAdd(&cnt[rec[rbase + i] >> 17], 1);
    __syncthreads();
    int v = (tid < ns) ? cnt[tid] + 1 : 0;   // +1 self-loop
    s[tid] = v;
    __syncthreads();
    for (int off = 1; off < THREADS; off <<= 1) {
        int t = (tid >= off) ? s[tid - off] : 0;
        __syncthreads();
        s[tid] += t;
        __syncthreads();
    }
    int excl = s[tid] - v;
    __syncthreads();
    s[tid] = excl;
    cur[tid] = excl;
    if (tid < ns) rowptr[n0 + tid] = cb + excl;
    if (b == nbuk - 1 && tid == 0) rowptr[Nn] = Etot;
    __syncthreads();
    for (int i = tid; i < cnt_e; i += THREADS) {
        unsigned int r = rec[rbase + i];
        int l = r >> 17;
        int slot = atomicAdd(&cur[l], 1);
        esrc[cb + slot] = (int)(r & 0x1FFFFu);
        edst[cb + slot] = n0 + l;
    }
    __syncthreads();
    if (tid < ns) {
        int slot = s[tid] + cnt[tid];
        esrc[cb + slot] = n0 + tid;   // self-loop last
        edst[cb + slot] = n0 + tid;
    }
}

// swizzled LDS index (ushort units) for x tiles
static __device__ __forceinline__ int xsw(int r, int c) {
    return (((r * 16 + (c >> 3)) ^ (r & 7)) << 3) | (c & 7);
}

// H = X(gathered) @ W via MFMA split-bf16 (3 terms). 64 rows x 128 cols/block.
__global__ __launch_bounds__(THREADS) void k_gemm_mfma(const float* __restrict__ X,
                                                       const int* __restrict__ idx,
                                                       const unsigned short* __restrict__ WBh,
                                                       const unsigned short* __restrict__ WBl,
                                                       const float* __restrict__ a_s,
                                                       const float* __restrict__ a_d,
                                                       unsigned short* __restrict__ outb,
                                                       float* __restrict__ as_,
                                                       float* __restrict__ ad_, int Nrows) {
    __shared__ unsigned short xh[64 * 128];
    __shared__ unsigned short xl[64 * 128];

    {
        int r = threadIdx.x >> 2;            // 0..63
        int c0 = (threadIdx.x & 3) * 32;
        int R = blockIdx.x * 64 + r;
        if (R < Nrows) {
            int g = idx ? idx[R] : R;
            const float4* xrow = (const float4*)(X + (size_t)g * 128);
            #pragma unroll
            for (int i = 0; i < 8; ++i) {
                float4 v = xrow[(c0 >> 2) + i];
                int c = c0 + i * 4;
                ushort4 hh, ll;
                hh.x = f2bf(v.x); ll.x = f2bf(v.x - bf2f(hh.x));
                hh.y = f2bf(v.y); ll.y = f2bf(v.y - bf2f(hh.y));
                hh.z = f2bf(v.z); ll.z = f2bf(v.z - bf2f(hh.z));
                hh.w = f2bf(v.w); ll.w = f2bf(v.w - bf2f(hh.w));
                int o = xsw(r, c);
                *(ushort4*)&xh[o] = hh;
                *(ushort4*)&xl[o] = ll;
            }
        } else {
            #pragma unroll
            for (int i = 0; i < 8; ++i) {
                int o = xsw(r, c0 + i * 4);
                *(ushort4*)&xh[o] = make_ushort4(0, 0, 0, 0);
                *(ushort4*)&xl[o] = make_ushort4(0, 0, 0, 0);
            }
        }
    }
    __syncthreads();

    int wid = threadIdx.x >> 6;
    int lane = threadIdx.x & 63;
    int nl = lane & 15;
    int g = lane >> 4;
    int arow = wid * 16 + nl;

    f32x4 acc[8];
    #pragma unroll
    for (int c = 0; c < 8; ++c) acc[c] = (f32x4){0.f, 0.f, 0.f, 0.f};

    #pragma unroll
    for (int t = 0; t < 4; ++t) {
        int ao = xsw(arow, t * 32 + g * 8);
        short8v ah = *(const short8v*)&xh[ao];
        short8v al = *(const short8v*)&xl[ao];
        #pragma unroll
        for (int c = 0; c < 8; ++c) {
            int bo = (((c * 4 + t) * 64) + lane) * 8;
            short8v bh = *(const short8v*)&WBh[bo];
            short8v bl = *(const short8v*)&WBl[bo];
            acc[c] = __builtin_amdgcn_mfma_f32_16x16x32_bf16(ah, bh, acc[c], 0, 0, 0);
            acc[c] = __builtin_amdgcn_mfma_f32_16x16x32_bf16(ah, bl, acc[c], 0, 0, 0);
            acc[c] = __builtin_amdgcn_mfma_f32_16x16x32_bf16(al, bh, acc[c], 0, 0, 0);
        }
    }

    float asv[8], adv[8];
    #pragma unroll
    for (int c = 0; c < 8; ++c) {
        asv[c] = a_s[c * 16 + nl];
        adv[c] = a_d[c * 16 + nl];
    }
    int Rb = blockIdx.x * 64 + wid * 16 + g * 4;
    #pragma unroll
    for (int r = 0; r < 4; ++r) {
        int R = Rb + r;
        bool ok = (R < Nrows);
        float ps = 0.f, pd = 0.f;
        #pragma unroll
        for (int c = 0; c < 8; ++c) {
            float v = acc[c][r];
            if (ok) outb[(size_t)R * 128 + c * 16 + nl] = f2bf(v);
            ps = fmaf(v, asv[c], ps);
            pd = fmaf(v, adv[c], pd);
        }
        #pragma unroll
        for (int o = 8; o; o >>= 1) {
            ps += __shfl_xor(ps, o);
            pd += __shfl_xor(pd, o);
        }
        if (ok && nl == 0) {
            as_[R] = ps;
            ad_[R] = pd;
        }
    }
}

// ---- edge-parallel attention coefficient pre-pass ----
__global__ __launch_bounds__(THREADS) void k_edgep(const float* __restrict__ as_,
                                                   const float* __restrict__ ad_,
                                                   const int* __restrict__ esrc,
                                                   const int* __restrict__ edst,
                                                   float* __restrict__ pbuf, int Etot) {
    int k = blockIdx.x * THREADS + threadIdx.x;
    if (k < Etot) {
        float e = as_[esrc[k]] + ad_[edst[k]];
        e = (e > 0.f) ? e : 0.2f * e;
        pbuf[k] = __expf(e);
    }
}

// wave per dst node: 8-deep pipelined bf16 h gather; p precomputed; + bias, relu.
__global__ __launch_bounds__(THREADS) void k_agg(const unsigned short* __restrict__ hb,
                                                 const float* __restrict__ pbuf,
                                                 const int* __restrict__ rowptr,
                                                 const int* __restrict__ esrc,
                                                 const float* __restrict__ bias,
                                                 float* __restrict__ out, int Nn) {
    int d = blockIdx.x * 4 + (threadIdx.x >> 6);
    int lane = threadIdx.x & 63;
    if (d >= Nn) return;
    int beg = rowptr[d], end = rowptr[d + 1];
    float z = 0.f, accx = 0.f, accy = 0.f;
    int k = beg;
    for (; k + 8 <= end; k += 8) {
        int sv[8];
        float pv[8];
        #pragma unroll
        for (int i = 0; i < 8; ++i) sv[i] = esrc[k + i];
        #pragma unroll
        for (int i = 0; i < 8; ++i) pv[i] = pbuf[k + i];
        unsigned int hv[8];
        #pragma unroll
        for (int i = 0; i < 8; ++i)
            hv[i] = *(const unsigned int*)&hb[(size_t)sv[i] * 128 + lane * 2];
        #pragma unroll
        for (int i = 0; i < 8; ++i) {
            z += pv[i];
            accx += pv[i] * bf2f((unsigned short)(hv[i] & 0xffffu));
            accy += pv[i] * bf2f((unsigned short)(hv[i] >> 16));
        }
    }
    for (; k < end; ++k) {
        int s = esrc[k];
        float p = pbuf[k];
        unsigned int hv = *(const unsigned int*)&hb[(size_t)s * 128 + lane * 2];
        z += p;
        accx += p * bf2f((unsigned short)(hv & 0xffffu));
        accy += p * bf2f((unsigned short)(hv >> 16));
    }
    float inv = 1.f / z;
    float2 o;
    o.x = fmaxf(accx * inv + bias[lane * 2 + 0], 0.f);
    o.y = fmaxf(accy * inv + bias[lane * 2 + 1], 0.f);
    *(float2*)&out[(size_t)d * 128 + lane * 2] = o;
}

// phase 1: grid (G, PSLICE); each block sums a strided slice of graph g's rows
__global__ __launch_bounds__(THREADS) void k_pool_partial(const float* __restrict__ x,
                                                          const int* __restrict__ batch,
                                                          float* __restrict__ part, int Nn) {
    int g = blockIdx.x;
    int s = blockIdx.y;
    int a = 0, b = Nn;
    while (a < b) { int mid = (a + b) >> 1; if (batch[mid] < g) a = mid + 1; else b = mid; }
    int lo = a;
    b = Nn;
    while (a < b) { int mid = (a + b) >> 1; if (batch[mid] < g + 1) a = mid + 1; else b = mid; }
    int hi = a;

    int j = threadIdx.x & 127;
    int half = threadIdx.x >> 7;
    float acc = 0.f;
    for (int n = lo + s * 2 + half; n < hi; n += 2 * PSLICE) acc += x[(size_t)n * 128 + j];
    __shared__ float sred[THREADS];
    sred[threadIdx.x] = acc;
    __syncthreads();
    if (half == 0) part[((size_t)g * PSLICE + s) * 128 + j] = sred[j] + sred[128 + j];
}

// phase 2: one block (128 threads) per graph: reduce partials, mean, logits
__global__ __launch_bounds__(128) void k_pool_final(const float* __restrict__ part,
                                                    const int* __restrict__ batch,
                                                    const float* __restrict__ Wc,
                                                    const float* __restrict__ bc,
                                                    float* __restrict__ out, int Nn, int Gn) {
    int g = blockIdx.x;
    int j = threadIdx.x;
    int a = 0, b = Nn;
    while (a < b) { int mid = (a + b) >> 1; if (batch[mid] < g) a = mid + 1; else b = mid; }
    int lo = a;
    b = Nn;
    while (a < b) { int mid = (a + b) >> 1; if (batch[mid] < g + 1) a = mid + 1; else b = mid; }
    int cnt = a - lo;

    float s = 0.f;
    #pragma unroll
    for (int t = 0; t < PSLICE; ++t) s += part[((size_t)g * PSLICE + t) * 128 + j];
    float mean = s / fmaxf((float)cnt, 1.f);
    out[Gn + (size_t)g * 128 + j] = mean;

    __shared__ float sred[128];
    sred[j] = mean * Wc[j];
    __syncthreads();
    for (int off = 64; off >= 1; off >>= 1) {
        if (j < off) sred[j] += sred[j + off];
        __syncthreads();
    }
    if (j == 0) out[g] = sred[0] + bc[0];
}

static inline size_t align256(size_t x) { return (x + 255) & ~(size_t)255; }

extern "C" void kernel_launch(void* const* d_in, const int* in_sizes, int n_in,
                              void* d_out, int out_size, void* d_ws, size_t ws_size,
                              hipStream_t stream) {
    const int* x_lex = (const int*)d_in[0];
    const int* eidx  = (const int*)d_in[1];
    const int* batch = (const int*)d_in[2];
    const float* emb = (const float*)d_in[3];
    const float* W1  = (const float*)d_in[4];
    const float* a_s1 = (const float*)d_in[5];
    const float* a_d1 = (const float*)d_in[6];
    const float* b1  = (const float*)d_in[7];
    const float* W2  = (const float*)d_in[8];
    const float* a_s2 = (const float*)d_in[9];
    const float* a_d2 = (const float*)d_in[10];
    const float* b2  = (const float*)d_in[11];
    const float* Wc  = (const float*)d_in[12];
    const float* bc  = (const float*)d_in[13];

    const int N = in_sizes[0];
    const int E = in_sizes[1] / 2;
    const int G = out_size / 129;      // out = [G logits] + [G x 128 pool]
    const int Etot = E + N;
    const int* esrc_in = eidx;
    const int* edst_in = eidx + E;
    const int NBUK = (N + BUK_S - 1) / BUK_S;   // 256 for N=50000

    // workspace carve
    char* p = (char*)d_ws;
    unsigned short* hb = (unsigned short*)p;  p += align256((size_t)N * 128 * 2);
    float* obuf = (float*)p;            p += align256((size_t)N * 128 * 4);
    float* as_  = (float*)p;            p += align256((size_t)N * 4);
    float* ad_  = (float*)p;            p += align256((size_t)N * 4);
    int* bcount = (int*)p;              p += align256((size_t)NBUK * 4);
    int* sbase  = (int*)p;              p += align256((size_t)NBUK * 4);
    int* gcur   = (int*)p;              p += align256((size_t)NBUK * 4);
    int* cbase  = (int*)p;              p += align256((size_t)NBUK * 4);
    int* rowptr = (int*)p;              p += align256((size_t)(N + 1) * 4);
    unsigned int* rec = (unsigned int*)p; p += align256((size_t)Etot * 4);  // reused as pbuf
    int* esrc   = (int*)p;              p += align256((size_t)Etot * 4);
    int* edst   = (int*)p;              p += align256((size_t)Etot * 4);
    float* part = (float*)p;            p += align256((size_t)G * PSLICE * 128 * 4);
    unsigned short* WBh1 = (unsigned short*)p; p += align256((size_t)128 * 128 * 2);
    unsigned short* WBl1 = (unsigned short*)p; p += align256((size_t)128 * 128 * 2);
    unsigned short* WBh2 = (unsigned short*)p; p += align256((size_t)128 * 128 * 2);
    unsigned short* WBl2 = (unsigned short*)p; p += align256((size_t)128 * 128 * 2);
    float* pbuf = (float*)rec;          // rec dead after k_csr

    const int chunk = (E + SORT_BLOCKS - 1) / SORT_BLOCKS;

    // ---- W split (fragment-major) ----
    k_wsplit<<<64, THREADS, 0, stream>>>(W1, WBh1, WBl1);
    k_wsplit<<<64, THREADS, 0, stream>>>(W2, WBh2, WBl2);

    // ---- CSR build via bucket sort ----
    hipMemsetAsync(bcount, 0, (size_t)NBUK * 4, stream);
    k_bukhist<<<SORT_BLOCKS, THREADS, 0, stream>>>(edst_in, bcount, E, chunk);
    k_bukscan<<<1, THREADS, 0, stream>>>(bcount, sbase, gcur, cbase, NBUK, N);
    k_bukscatter<<<SORT_BLOCKS, THREADS, 0, stream>>>(esrc_in, edst_in, gcur, rec, E, chunk);
    k_csr<<<NBUK, THREADS, 0, stream>>>(rec, sbase, bcount, cbase, rowptr, esrc, edst, N, NBUK, Etot);

    const int gemm_grid = (N + 63) / 64;
    const int node_grid = (N + 3) / 4;
    const int edge_grid = (Etot + THREADS - 1) / THREADS;

    // ---- layer 1 ----
    k_gemm_mfma<<<gemm_grid, THREADS, 0, stream>>>(emb, x_lex, WBh1, WBl1, a_s1, a_d1, hb, as_, ad_, N);
    k_edgep<<<edge_grid, THREADS, 0, stream>>>(as_, ad_, esrc, edst, pbuf, Etot);
    k_agg<<<node_grid, THREADS, 0, stream>>>(hb, pbuf, rowptr, esrc, b1, obuf, N);

    // ---- layer 2 ----
    k_gemm_mfma<<<gemm_grid, THREADS, 0, stream>>>(obuf, nullptr, WBh2, WBl2, a_s2, a_d2, hb, as_, ad_, N);
    k_edgep<<<edge_grid, THREADS, 0, stream>>>(as_, ad_, esrc, edst, pbuf, Etot);
    k_agg<<<node_grid, THREADS, 0, stream>>>(hb, pbuf, rowptr, esrc, b2, obuf, N);

    // ---- pool + logits ----
    k_pool_partial<<<dim3(G, PSLICE), THREADS, 0, stream>>>(obuf, batch, part, N);
    k_pool_final<<<G, 128, 0, stream>>>(part, batch, Wc, bc, (float*)d_out, N, G);
}